// Round 13
// baseline (165.669 us; speedup 1.0000x reference)
//
#include <hip/hip_runtime.h>

#define H_NUM 16
#define HD    64
#define SQ    2048
#define HID   1024
#define MTOK  8192   // B*S

typedef __attribute__((ext_vector_type(8))) short bf16x8;
typedef __attribute__((ext_vector_type(4))) short s16x4;
typedef __attribute__((ext_vector_type(4))) float f32x4;

__device__ __forceinline__ short f2bf(float f) {
  union { float f; unsigned u; } v; v.f = f;
  unsigned r = v.u + 0x7fffu + ((v.u >> 16) & 1u);
  return (short)(r >> 16);
}

__device__ __forceinline__ float fexp2(float x) {
#if __has_builtin(__builtin_amdgcn_exp2f)
  return __builtin_amdgcn_exp2f(x);
#else
  return exp2f(x);
#endif
}

__device__ __forceinline__ void gload_lds16(const short* g, short* l) {
  __builtin_amdgcn_global_load_lds(
      (const __attribute__((address_space(1))) void*)g,
      (__attribute__((address_space(3))) void*)l, 16, 0, 0);
}

// ---------- fused pre-pass: hs f32->bf16 + two weight transposes ----------
__global__ __launch_bounds__(256) void k_pre(
    const float* __restrict__ hs, short* __restrict__ hs_bf,
    const float* __restrict__ wqkv, short* __restrict__ wqkv_t,
    const float* __restrict__ wd, short* __restrict__ wd_t) {
  __shared__ float t[32][33];
  const int b = blockIdx.x, tid = threadIdx.x;
  if (b < 8192) {  // cvt: 8192 blocks x 256 thr x 4 floats
    int i = b * 256 + tid;
    float4 f = ((const float4*)hs)[i];
    s16x4 o = { f2bf(f.x), f2bf(f.y), f2bf(f.z), f2bf(f.w) };
    ((s16x4*)hs_bf)[i] = o;
    return;
  }
  // transpose: out[c][r] = bf16(in[r][c]), packed 4-r stores
  const float* in; short* out; int R, C, bx, by;
  if (b < 8192 + 3072) {
    int idx = b - 8192; in = wqkv; out = wqkv_t; R = 1024; C = 3072;
    bx = idx % 96; by = idx / 96;
  } else {
    int idx = b - 11264; in = wd; out = wd_t; R = 1024; C = 1024;
    bx = idx & 31; by = idx >> 5;
  }
  const int c0 = bx * 32, r0 = by * 32;
  const int tx = tid & 31, ty = tid >> 5;
#pragma unroll
  for (int i = 0; i < 4; i++)
    t[ty + 8 * i][tx] = in[(size_t)(r0 + ty + 8 * i) * C + c0 + tx];
  __syncthreads();
  const int cc = tid >> 3, j = tid & 7;  // 32 cols x 8 quads
  s16x4 pk;
#pragma unroll
  for (int p = 0; p < 4; ++p) pk[p] = f2bf(t[4 * j + p][cc]);
  *(s16x4*)&out[(size_t)(c0 + cc) * R + r0 + 4 * j] = pk;
}

// ---------- GEMM: C[M,N] = A[M,K] @ Bt[N,K]^T + bias ----------
// r4-verified m97-style 128x128; (256,4) bounds -> 64 VGPR, ~2.7 blk/CU (r12).
template <int EPI>
__global__ __launch_bounds__(256, 4) void k_gemm(
    const short* __restrict__ A, const short* __restrict__ Bt,
    const float* __restrict__ bias,
    short* __restrict__ qbuf, short* __restrict__ kbuf, short* __restrict__ vtbuf,
    float* __restrict__ outf, int Kd) {
  __shared__ short as[128][64];
  __shared__ short bs[128][64];
  const int tid = threadIdx.x;
  const int w = tid >> 6, l = tid & 63;
  const int lr = l & 15, lk = l >> 4;
  const int wr = w >> 1, wc = w & 1;
  const int nwg = gridDim.x * gridDim.y;
  const int lin = blockIdx.y * gridDim.x + blockIdx.x;
  const int swz = (lin & 7) * (nwg >> 3) + (lin >> 3);
  const int m0 = (swz / gridDim.x) * 128, n0 = (swz % gridDim.x) * 128;

  f32x4 acc[4][4] = {};

  for (int kt = 0; kt < Kd; kt += 64) {
#pragma unroll
    for (int rnd = 0; rnd < 4; ++rnd) {
      int e = rnd * 2048 + w * 512 + l * 8;
      int row = e >> 6, col = e & 63;
      gload_lds16(A + (size_t)(m0 + row) * Kd + kt + col,
                  &as[0][0] + rnd * 2048 + w * 512);
      gload_lds16(Bt + (size_t)(n0 + row) * Kd + kt + col,
                  &bs[0][0] + rnd * 2048 + w * 512);
    }
    __syncthreads();
#pragma unroll
    for (int kk = 0; kk < 2; ++kk) {
      bf16x8 af[4], bf[4];
#pragma unroll
      for (int m = 0; m < 4; ++m)
        af[m] = *(const bf16x8*)&as[wr * 64 + m * 16 + lr][kk * 32 + lk * 8];
#pragma unroll
      for (int n = 0; n < 4; ++n)
        bf[n] = *(const bf16x8*)&bs[wc * 64 + n * 16 + lr][kk * 32 + lk * 8];
      __builtin_amdgcn_s_setprio(1);
#pragma unroll
      for (int m = 0; m < 4; ++m)
#pragma unroll
        for (int n = 0; n < 4; ++n)
          acc[m][n] = __builtin_amdgcn_mfma_f32_16x16x32_bf16(af[m], bf[n], acc[m][n], 0, 0, 0);
      __builtin_amdgcn_s_setprio(0);
    }
    __syncthreads();
  }

  // C layout: col=lane&15, row=(lane>>4)*4+reg  [m89]
  const float SCLQ = 0.125f * 1.44269504088896341f;
#pragma unroll
  for (int n = 0; n < 4; ++n) {
    const int col = n0 + wc * 64 + n * 16 + lr;
    const float bv = bias[col];
    if (EPI == 1) {
#pragma unroll
      for (int m = 0; m < 4; ++m) {
        int row = m0 + wr * 64 + m * 16 + lk * 4;
#pragma unroll
        for (int r = 0; r < 4; ++r)
          outf[(size_t)(row + r) * HID + col] = acc[m][n][r] + bv;
      }
    } else if (col < HID) {  // K: [BH][S][D]
      int h = col >> 6, d = col & 63;
#pragma unroll
      for (int m = 0; m < 4; ++m) {
        int row = m0 + wr * 64 + m * 16 + lk * 4;
        int b = row >> 11, s = row & 2047;
#pragma unroll
        for (int r = 0; r < 4; ++r)
          kbuf[((size_t)(b * H_NUM + h) * SQ + s + r) * HD + d] = f2bf(acc[m][n][r] + bv);
      }
    } else if (col < 2 * HID) {  // V^T: [BH][D][S], packed 4-s stores
      int f = col - HID, h = f >> 6, d = f & 63;
#pragma unroll
      for (int m = 0; m < 4; ++m) {
        int row = m0 + wr * 64 + m * 16 + lk * 4;
        int b = row >> 11, s = row & 2047;
        s16x4 pk;
#pragma unroll
        for (int r = 0; r < 4; ++r) pk[r] = f2bf(acc[m][n][r] + bv);
        *(s16x4*)&vtbuf[((size_t)(b * H_NUM + h) * HD + d) * SQ + s] = pk;
      }
    } else {  // Q: [BH][S][D], pre-scaled into exp2 domain
      int f = col - 2 * HID, h = f >> 6, d = f & 63;
#pragma unroll
      for (int m = 0; m < 4; ++m) {
        int row = m0 + wr * 64 + m * 16 + lk * 4;
        int b = row >> 11, s = row & 2047;
#pragma unroll
        for (int r = 0; r < 4; ++r)
          qbuf[((size_t)(b * H_NUM + h) * SQ + s + r) * HD + d] = f2bf((acc[m][n][r] + bv) * SCLQ);
      }
    }
  }
}

// ---------- GEMM2: 128x64 tile (out-proj): grid 1024 -> 4 blocks/CU ----------
// Same verified structure, BN=64: 4 waves as 2M x 2N, wave 64x32, acc[4][2].
__global__ __launch_bounds__(256, 4) void k_gemm2(
    const short* __restrict__ A, const short* __restrict__ Bt,
    const float* __restrict__ bias, float* __restrict__ outf, int Kd) {
  __shared__ short as[128][64];
  __shared__ short bs[64][64];
  const int tid = threadIdx.x;
  const int w = tid >> 6, l = tid & 63;
  const int lr = l & 15, lk = l >> 4;
  const int wm = w >> 1, wn = w & 1;
  const int nwg = gridDim.x * gridDim.y;
  const int lin = blockIdx.y * gridDim.x + blockIdx.x;
  const int swz = (lin & 7) * (nwg >> 3) + (lin >> 3);
  const int m0 = (swz / gridDim.x) * 128, n0 = (swz % gridDim.x) * 64;

  f32x4 acc[4][2] = {};

  for (int kt = 0; kt < Kd; kt += 64) {
#pragma unroll
    for (int rnd = 0; rnd < 4; ++rnd) {
      int e = rnd * 2048 + w * 512 + l * 8;
      int row = e >> 6, col = e & 63;
      gload_lds16(A + (size_t)(m0 + row) * Kd + kt + col,
                  &as[0][0] + rnd * 2048 + w * 512);
    }
#pragma unroll
    for (int rnd = 0; rnd < 2; ++rnd) {
      int e = rnd * 2048 + w * 512 + l * 8;
      int row = e >> 6, col = e & 63;
      gload_lds16(Bt + (size_t)(n0 + row) * Kd + kt + col,
                  &bs[0][0] + rnd * 2048 + w * 512);
    }
    __syncthreads();
#pragma unroll
    for (int kk = 0; kk < 2; ++kk) {
      bf16x8 af[4], bf[2];
#pragma unroll
      for (int m = 0; m < 4; ++m)
        af[m] = *(const bf16x8*)&as[wm * 64 + m * 16 + lr][kk * 32 + lk * 8];
#pragma unroll
      for (int n = 0; n < 2; ++n)
        bf[n] = *(const bf16x8*)&bs[wn * 32 + n * 16 + lr][kk * 32 + lk * 8];
      __builtin_amdgcn_s_setprio(1);
#pragma unroll
      for (int m = 0; m < 4; ++m)
#pragma unroll
        for (int n = 0; n < 2; ++n)
          acc[m][n] = __builtin_amdgcn_mfma_f32_16x16x32_bf16(af[m], bf[n], acc[m][n], 0, 0, 0);
      __builtin_amdgcn_s_setprio(0);
    }
    __syncthreads();
  }

#pragma unroll
  for (int n = 0; n < 2; ++n) {
    const int col = n0 + wn * 32 + n * 16 + lr;
    const float bv = bias[col];
#pragma unroll
    for (int m = 0; m < 4; ++m) {
      int row = m0 + wm * 64 + m * 16 + lk * 4;
#pragma unroll
      for (int r = 0; r < 4; ++r)
        outf[(size_t)(row + r) * HID + col] = acc[m][n][r] + bv;
    }
  }
}

// ---------- flash attention, causal (r9/r12-verified) ----------
__global__ __launch_bounds__(512) void k_attn(
    const short* __restrict__ Q, const short* __restrict__ K,
    const short* __restrict__ Vt, short* __restrict__ ctx) {
  __shared__ short ks[2][4096];
  __shared__ short vs[2][4096];
  __shared__ short ps[8][16][72];
  const int tid = threadIdx.x;
  const int w = tid >> 6, l = tid & 63;
  const int lr = l & 15, lk = l >> 4;

  const int lin = blockIdx.x;          // 0..1023
  const int xcd = lin & 7;
  const int idx = lin >> 3;            // 0..127
  const int qt  = 15 - (idx >> 3);     // longest first
  const int bh  = xcd * 8 + (idx & 7); // 8 bh per XCD chunk (4MB K+V in L2)
  const int bb = bh >> 4, hh = bh & 15;
  const size_t base = (size_t)bh * (SQ * HD);
  const float THR = 11.5416f;  // 8 * log2(e)

  const int nt = 2 * qt + 2;
  const int diag = 2 * qt + (w >> 2);  // wave-uniform diagonal tile
  const int qr = qt * 128 + w * 16;

  const int srow = tid >> 3;
  const int scol = ((tid & 7) * 8) ^ ((srow & 7) * 8);
  const short* kg0 = K + base + srow * HD + scol;
  const short* vg0 = Vt + base + (size_t)srow * SQ + scol;
  short* kld = &ks[0][0] + tid * 8;
  short* vld = &vs[0][0] + tid * 8;
  const int rdswz = (lr & 7) * 8;

  bf16x8 qf[2];
#pragma unroll
  for (int kk = 0; kk < 2; ++kk)
    qf[kk] = *(const bf16x8*)(Q + base + (size_t)(qr + lr) * HD + kk * 32 + lk * 8);

  f32x4 o[4] = {};
  float mrun = -3.0e4f, lsum = 0.f;  // per lane: q-row = qr + lr

  int buf = 0;
  gload_lds16(kg0, kld);
  gload_lds16(vg0, vld);
  __syncthreads();

  for (int t = 0; t < nt; ++t) {
    if (t + 1 < nt) {  // stage next tile (overlaps compute)
      gload_lds16(kg0 + (t + 1) * 4096, kld + (buf ^ 1) * 4096);
      gload_lds16(vg0 + (t + 1) * 64, vld + (buf ^ 1) * 4096);
    }
    if (t <= diag) {
      const short* kb = &ks[buf][0];
      const short* vb = &vs[buf][0];
      f32x4 sf[4] = {};
      __builtin_amdgcn_s_setprio(1);
#pragma unroll
      for (int kk = 0; kk < 2; ++kk)
#pragma unroll
        for (int n = 0; n < 4; ++n) {
          bf16x8 kf = *(const bf16x8*)(kb + (n * 16 + lr) * 64 + ((kk * 32 + lk * 8) ^ rdswz));
          sf[n] = __builtin_amdgcn_mfma_f32_16x16x32_bf16(kf, qf[kk], sf[n], 0, 0, 0);
        }
      __builtin_amdgcn_s_setprio(0);

      if (t == diag) {  // diagonal mask
        const int qg = qr + lr;
#pragma unroll
        for (int n = 0; n < 4; ++n) {
          int kg = t * 64 + n * 16 + lk * 4;
#pragma unroll
          for (int r = 0; r < 4; ++r)
            if (kg + r > qg) sf[n][r] = -14426.95f;  // -10000 * log2(e)
        }
      }

      float m0 = sf[0][0];
#pragma unroll
      for (int n = 0; n < 4; ++n)
#pragma unroll
        for (int r = 0; r < 4; ++r) m0 = fmaxf(m0, sf[n][r]);
      m0 = fmaxf(m0, __shfl_xor(m0, 16));
      m0 = fmaxf(m0, __shfl_xor(m0, 32));

      if (__any(m0 > mrun + THR)) {  // T13 defer-rescale (rare)
        float mn = fmaxf(mrun, m0);
        float sc = fexp2(mrun - mn);
        float scq[4];
#pragma unroll
        for (int r = 0; r < 4; ++r) scq[r] = __shfl(sc, lk * 4 + r);
#pragma unroll
        for (int nd = 0; nd < 4; ++nd)
#pragma unroll
          for (int r = 0; r < 4; ++r) o[nd][r] *= scq[r];
        lsum *= sc;
        mrun = mn;
      }

      float rs = 0.f;
#pragma unroll
      for (int n = 0; n < 4; ++n) {
        s16x4 pk;
#pragma unroll
        for (int r = 0; r < 4; ++r) {
          float p = fexp2(sf[n][r] - mrun);
          rs += p;
          pk[r] = (short)(__float_as_uint(p) >> 16);
        }
        *(s16x4*)&ps[w][lr][n * 16 + lk * 4] = pk;
      }
      lsum += rs;

      bf16x8 pa[2];
#pragma unroll
      for (int kk = 0; kk < 2; ++kk)
        pa[kk] = *(const bf16x8*)&ps[w][lr][kk * 32 + lk * 8];

      __builtin_amdgcn_s_setprio(1);
#pragma unroll
      for (int kk = 0; kk < 2; ++kk)
#pragma unroll
        for (int nd = 0; nd < 4; ++nd) {
          bf16x8 vf = *(const bf16x8*)(vb + (nd * 16 + lr) * 64 + ((kk * 32 + lk * 8) ^ rdswz));
          o[nd] = __builtin_amdgcn_mfma_f32_16x16x32_bf16(pa[kk], vf, o[nd], 0, 0, 0);
        }
      __builtin_amdgcn_s_setprio(0);
    }
    __syncthreads();
    buf ^= 1;
  }

  lsum += __shfl_xor(lsum, 16);
  lsum += __shfl_xor(lsum, 32);
  float inv = 1.0f / lsum;
  float invq[4];
#pragma unroll
  for (int r = 0; r < 4; ++r) invq[r] = __shfl(inv, lk * 4 + r);
#pragma unroll
  for (int nd = 0; nd < 4; ++nd)
#pragma unroll
    for (int r = 0; r < 4; ++r) {
      int s = qr + lk * 4 + r;
      ctx[((size_t)(bb * SQ + s)) * HID + hh * 64 + nd * 16 + lr] = f2bf(o[nd][r] * invq[r]);
    }
}

extern "C" void kernel_launch(void* const* d_in, const int* in_sizes, int n_in,
                              void* d_out, int out_size, void* d_ws, size_t ws_size,
                              hipStream_t stream) {
  const float* hs   = (const float*)d_in[0];
  const float* wqkv = (const float*)d_in[1];
  const float* bqkv = (const float*)d_in[2];
  const float* wd   = (const float*)d_in[3];
  const float* bd   = (const float*)d_in[4];
  float* out = (float*)d_out;
  char* ws = (char*)d_ws;
  const size_t MB = 1u << 20;

  short* hs_bf  = (short*)(ws);            // 16 MB
  short* wqkv_t = (short*)(ws + 16 * MB);  //  6 MB
  short* wd_t   = (short*)(ws + 22 * MB);  //  2 MB
  short* qbuf   = (short*)(ws + 24 * MB);  // 16 MB: [64][2048][64]
  short* kbuf   = (short*)(ws + 40 * MB);  // 16 MB: [64][2048][64]
  short* vtbuf  = (short*)(ws + 56 * MB);  // 16 MB: [64][64][2048]
  short* ctx    = (short*)(ws + 72 * MB);  // 16 MB: [8192][1024]

  k_pre<<<12288, 256, 0, stream>>>(hs, hs_bf, wqkv, wqkv_t, wd, wd_t);
  k_gemm<0><<<dim3(24, 64), 256, 0, stream>>>(hs_bf, wqkv_t, bqkv,
                                              qbuf, kbuf, vtbuf, nullptr, 1024);
  k_attn<<<1024, 512, 0, stream>>>(qbuf, kbuf, vtbuf, ctx);
  k_gemm2<<<dim3(16, 64), 256, 0, stream>>>(ctx, wd_t, bd, out, 1024);
}

// Round 14
// 162.014 us; speedup vs baseline: 1.0226x; 1.0226x over previous
//
#include <hip/hip_runtime.h>

#define H_NUM 16
#define HD    64
#define SQ    2048
#define HID   1024
#define MTOK  8192   // B*S

typedef __attribute__((ext_vector_type(8))) short bf16x8;
typedef __attribute__((ext_vector_type(4))) short s16x4;
typedef __attribute__((ext_vector_type(4))) float f32x4;

__device__ __forceinline__ short f2bf(float f) {
  union { float f; unsigned u; } v; v.f = f;
  unsigned r = v.u + 0x7fffu + ((v.u >> 16) & 1u);
  return (short)(r >> 16);
}

__device__ __forceinline__ float fexp2(float x) {
#if __has_builtin(__builtin_amdgcn_exp2f)
  return __builtin_amdgcn_exp2f(x);
#else
  return exp2f(x);
#endif
}

__device__ __forceinline__ void gload_lds16(const short* g, short* l) {
  __builtin_amdgcn_global_load_lds(
      (const __attribute__((address_space(1))) void*)g,
      (__attribute__((address_space(3))) void*)l, 16, 0, 0);
}

// ---------- fused pre-pass: hs f32->bf16 + two weight transposes ----------
__global__ __launch_bounds__(256) void k_pre(
    const float* __restrict__ hs, short* __restrict__ hs_bf,
    const float* __restrict__ wqkv, short* __restrict__ wqkv_t,
    const float* __restrict__ wd, short* __restrict__ wd_t) {
  __shared__ float t[32][33];
  const int b = blockIdx.x, tid = threadIdx.x;
  if (b < 8192) {  // cvt: 8192 blocks x 256 thr x 4 floats
    int i = b * 256 + tid;
    float4 f = ((const float4*)hs)[i];
    s16x4 o = { f2bf(f.x), f2bf(f.y), f2bf(f.z), f2bf(f.w) };
    ((s16x4*)hs_bf)[i] = o;
    return;
  }
  // transpose: out[c][r] = bf16(in[r][c])
  const float* in; short* out; int R, C, bx, by;
  if (b < 8192 + 3072) {
    int idx = b - 8192; in = wqkv; out = wqkv_t; R = 1024; C = 3072;
    bx = idx % 96; by = idx / 96;
  } else {
    int idx = b - 11264; in = wd; out = wd_t; R = 1024; C = 1024;
    bx = idx & 31; by = idx >> 5;
  }
  const int c0 = bx * 32, r0 = by * 32;
  const int tx = tid & 31, ty = tid >> 5;
#pragma unroll
  for (int i = 0; i < 4; i++)
    t[ty + 8 * i][tx] = in[(size_t)(r0 + ty + 8 * i) * C + c0 + tx];
  __syncthreads();
#pragma unroll
  for (int i = 0; i < 4; i++)
    out[(size_t)(c0 + ty + 8 * i) * R + r0 + tx] = f2bf(t[tx][ty + 8 * i]);
}

// ---------- GEMM: C[M,N] = A[M,K] @ Bt[N,K]^T + bias ----------
// r4-verified m97-style 128x128; launch_bounds(256,4) -> 64 VGPR,
// ~2.7 blocks/CU co-resident (r12: 80.7 -> 74.8 us, Occupancy 26 -> 33%).
template <int EPI>
__global__ __launch_bounds__(256, 4) void k_gemm(
    const short* __restrict__ A, const short* __restrict__ Bt,
    const float* __restrict__ bias,
    short* __restrict__ qbuf, short* __restrict__ kbuf, short* __restrict__ vtbuf,
    float* __restrict__ outf, int Kd) {
  __shared__ short as[128][64];
  __shared__ short bs[128][64];
  const int tid = threadIdx.x;
  const int w = tid >> 6, l = tid & 63;
  const int lr = l & 15, lk = l >> 4;
  const int wr = w >> 1, wc = w & 1;
  // bijective XCD swizzle (nwg % 8 == 0 for both launches)
  const int nwg = gridDim.x * gridDim.y;
  const int lin = blockIdx.y * gridDim.x + blockIdx.x;
  const int swz = (lin & 7) * (nwg >> 3) + (lin >> 3);
  const int m0 = (swz / gridDim.x) * 128, n0 = (swz % gridDim.x) * 128;

  f32x4 acc[4][4] = {};

  for (int kt = 0; kt < Kd; kt += 64) {
#pragma unroll
    for (int rnd = 0; rnd < 4; ++rnd) {
      int e = rnd * 2048 + w * 512 + l * 8;
      int row = e >> 6, col = e & 63;
      gload_lds16(A + (size_t)(m0 + row) * Kd + kt + col,
                  &as[0][0] + rnd * 2048 + w * 512);
      gload_lds16(Bt + (size_t)(n0 + row) * Kd + kt + col,
                  &bs[0][0] + rnd * 2048 + w * 512);
    }
    __syncthreads();
#pragma unroll
    for (int kk = 0; kk < 2; ++kk) {
      bf16x8 af[4], bf[4];
#pragma unroll
      for (int m = 0; m < 4; ++m)
        af[m] = *(const bf16x8*)&as[wr * 64 + m * 16 + lr][kk * 32 + lk * 8];
#pragma unroll
      for (int n = 0; n < 4; ++n)
        bf[n] = *(const bf16x8*)&bs[wc * 64 + n * 16 + lr][kk * 32 + lk * 8];
      __builtin_amdgcn_s_setprio(1);
#pragma unroll
      for (int m = 0; m < 4; ++m)
#pragma unroll
        for (int n = 0; n < 4; ++n)
          acc[m][n] = __builtin_amdgcn_mfma_f32_16x16x32_bf16(af[m], bf[n], acc[m][n], 0, 0, 0);
      __builtin_amdgcn_s_setprio(0);
    }
    __syncthreads();
  }

  // C layout: col=lane&15, row=(lane>>4)*4+reg  [m89]
  const float SCLQ = 0.125f * 1.44269504088896341f;
#pragma unroll
  for (int n = 0; n < 4; ++n) {
    const int col = n0 + wc * 64 + n * 16 + lr;
    const float bv = bias[col];
    if (EPI == 1) {
#pragma unroll
      for (int m = 0; m < 4; ++m) {
        int row = m0 + wr * 64 + m * 16 + lk * 4;
#pragma unroll
        for (int r = 0; r < 4; ++r)
          outf[(size_t)(row + r) * HID + col] = acc[m][n][r] + bv;
      }
    } else if (col < HID) {  // K: [BH][S][D]
      int h = col >> 6, d = col & 63;
#pragma unroll
      for (int m = 0; m < 4; ++m) {
        int row = m0 + wr * 64 + m * 16 + lk * 4;
        int b = row >> 11, s = row & 2047;
#pragma unroll
        for (int r = 0; r < 4; ++r)
          kbuf[((size_t)(b * H_NUM + h) * SQ + s + r) * HD + d] = f2bf(acc[m][n][r] + bv);
      }
    } else if (col < 2 * HID) {  // V^T: [BH][D][S], packed 4-s stores
      int f = col - HID, h = f >> 6, d = f & 63;
#pragma unroll
      for (int m = 0; m < 4; ++m) {
        int row = m0 + wr * 64 + m * 16 + lk * 4;
        int b = row >> 11, s = row & 2047;
        s16x4 pk;
#pragma unroll
        for (int r = 0; r < 4; ++r) pk[r] = f2bf(acc[m][n][r] + bv);
        *(s16x4*)&vtbuf[((size_t)(b * H_NUM + h) * HD + d) * SQ + s] = pk;
      }
    } else {  // Q: [BH][S][D], pre-scaled into exp2 domain
      int f = col - 2 * HID, h = f >> 6, d = f & 63;
#pragma unroll
      for (int m = 0; m < 4; ++m) {
        int row = m0 + wr * 64 + m * 16 + lk * 4;
        int b = row >> 11, s = row & 2047;
#pragma unroll
        for (int r = 0; r < 4; ++r)
          qbuf[((size_t)(b * H_NUM + h) * SQ + s + r) * HD + d] = f2bf((acc[m][n][r] + bv) * SCLQ);
      }
    }
  }
}

// ---------- flash attention, causal (r9/r12-verified) ----------
// ONE 128-row q-tile per block (grid 1024), longest-first in XCD-bijective
// chunks, 8 waves x 16 q-rows, K/V double-buffered swizzled LDS.
// Swapped QK^T -> in-lane softmax, defer-rescale, packed b64 P writes
// (P roundtrip via per-wave LDS: 6 DS ops < 16 bpermutes, r11 lesson).
__global__ __launch_bounds__(512) void k_attn(
    const short* __restrict__ Q, const short* __restrict__ K,
    const short* __restrict__ Vt, short* __restrict__ ctx) {
  __shared__ short ks[2][4096];
  __shared__ short vs[2][4096];
  __shared__ short ps[8][16][72];
  const int tid = threadIdx.x;
  const int w = tid >> 6, l = tid & 63;
  const int lr = l & 15, lk = l >> 4;

  const int lin = blockIdx.x;          // 0..1023
  const int xcd = lin & 7;
  const int idx = lin >> 3;            // 0..127
  const int qt  = 15 - (idx >> 3);     // longest first
  const int bh  = xcd * 8 + (idx & 7); // 8 bh per XCD chunk (4MB K+V in L2)
  const int bb = bh >> 4, hh = bh & 15;
  const size_t base = (size_t)bh * (SQ * HD);
  const float THR = 11.5416f;  // 8 * log2(e)

  const int nt = 2 * qt + 2;
  const int diag = 2 * qt + (w >> 2);  // wave-uniform diagonal tile
  const int qr = qt * 128 + w * 16;

  // staging: thread owns one 16B granule; source column pre-swizzled
  const int srow = tid >> 3;
  const int scol = ((tid & 7) * 8) ^ ((srow & 7) * 8);
  const short* kg0 = K + base + srow * HD + scol;
  const short* vg0 = Vt + base + (size_t)srow * SQ + scol;
  short* kld = &ks[0][0] + tid * 8;
  short* vld = &vs[0][0] + tid * 8;
  const int rdswz = (lr & 7) * 8;

  bf16x8 qf[2];
#pragma unroll
  for (int kk = 0; kk < 2; ++kk)
    qf[kk] = *(const bf16x8*)(Q + base + (size_t)(qr + lr) * HD + kk * 32 + lk * 8);

  f32x4 o[4] = {};
  float mrun = -3.0e4f, lsum = 0.f;  // per lane: q-row = qr + lr

  // prologue: stage tile 0
  int buf = 0;
  gload_lds16(kg0, kld);
  gload_lds16(vg0, vld);
  __syncthreads();

  for (int t = 0; t < nt; ++t) {
    if (t + 1 < nt) {  // stage next tile (overlaps compute)
      gload_lds16(kg0 + (t + 1) * 4096, kld + (buf ^ 1) * 4096);
      gload_lds16(vg0 + (t + 1) * 64, vld + (buf ^ 1) * 4096);
    }
    if (t <= diag) {
      const short* kb = &ks[buf][0];
      const short* vb = &vs[buf][0];
      // S^T = K @ Q'^T : sf[n][r] = S[k=t*64+n*16+lk*4+r][q=qr+lr]
      f32x4 sf[4] = {};
      __builtin_amdgcn_s_setprio(1);
#pragma unroll
      for (int kk = 0; kk < 2; ++kk)
#pragma unroll
        for (int n = 0; n < 4; ++n) {
          bf16x8 kf = *(const bf16x8*)(kb + (n * 16 + lr) * 64 + ((kk * 32 + lk * 8) ^ rdswz));
          sf[n] = __builtin_amdgcn_mfma_f32_16x16x32_bf16(kf, qf[kk], sf[n], 0, 0, 0);
        }
      __builtin_amdgcn_s_setprio(0);

      if (t == diag) {  // diagonal mask
        const int qg = qr + lr;
#pragma unroll
        for (int n = 0; n < 4; ++n) {
          int kg = t * 64 + n * 16 + lk * 4;
#pragma unroll
          for (int r = 0; r < 4; ++r)
            if (kg + r > qg) sf[n][r] = -14426.95f;  // -10000 * log2(e)
        }
      }

      // in-lane row max over 16 regs, then across the lk group
      float m0 = sf[0][0];
#pragma unroll
      for (int n = 0; n < 4; ++n)
#pragma unroll
        for (int r = 0; r < 4; ++r) m0 = fmaxf(m0, sf[n][r]);
      m0 = fmaxf(m0, __shfl_xor(m0, 16));
      m0 = fmaxf(m0, __shfl_xor(m0, 32));

      if (__any(m0 > mrun + THR)) {  // T13 defer-rescale (rare)
        float mn = fmaxf(mrun, m0);
        float sc = fexp2(mrun - mn);
        float scq[4];
#pragma unroll
        for (int r = 0; r < 4; ++r) scq[r] = __shfl(sc, lk * 4 + r);
#pragma unroll
        for (int nd = 0; nd < 4; ++nd)
#pragma unroll
          for (int r = 0; r < 4; ++r) o[nd][r] *= scq[r];
        lsum *= sc;
        mrun = mn;
      }

      // P = exp2(S' - mrun); packed b64 P writes; per-lane partial lsum
      float rs = 0.f;
#pragma unroll
      for (int n = 0; n < 4; ++n) {
        s16x4 pk;
#pragma unroll
        for (int r = 0; r < 4; ++r) {
          float p = fexp2(sf[n][r] - mrun);
          rs += p;
          pk[r] = (short)(__float_as_uint(p) >> 16);
        }
        *(s16x4*)&ps[w][lr][n * 16 + lk * 4] = pk;
      }
      lsum += rs;

      // reload P as MFMA A-fragment (same-wave LDS roundtrip)
      bf16x8 pa[2];
#pragma unroll
      for (int kk = 0; kk < 2; ++kk)
        pa[kk] = *(const bf16x8*)&ps[w][lr][kk * 32 + lk * 8];

      // O += P @ V
      __builtin_amdgcn_s_setprio(1);
#pragma unroll
      for (int kk = 0; kk < 2; ++kk)
#pragma unroll
        for (int nd = 0; nd < 4; ++nd) {
          bf16x8 vf = *(const bf16x8*)(vb + (nd * 16 + lr) * 64 + ((kk * 32 + lk * 8) ^ rdswz));
          o[nd] = __builtin_amdgcn_mfma_f32_16x16x32_bf16(pa[kk], vf, o[nd], 0, 0, 0);
        }
      __builtin_amdgcn_s_setprio(0);
    }
    __syncthreads();  // drains staging vmcnt + protects buf swap
    buf ^= 1;
  }

  // epilogue: reduce lsum across lk group once; o[nd][r] = O[qr+lk*4+r][nd*16+lr]
  lsum += __shfl_xor(lsum, 16);
  lsum += __shfl_xor(lsum, 32);
  float inv = 1.0f / lsum;
  float invq[4];
#pragma unroll
  for (int r = 0; r < 4; ++r) invq[r] = __shfl(inv, lk * 4 + r);
#pragma unroll
  for (int nd = 0; nd < 4; ++nd)
#pragma unroll
    for (int r = 0; r < 4; ++r) {
      int s = qr + lk * 4 + r;
      ctx[((size_t)(bb * SQ + s)) * HID + hh * 64 + nd * 16 + lr] = f2bf(o[nd][r] * invq[r]);
    }
}

extern "C" void kernel_launch(void* const* d_in, const int* in_sizes, int n_in,
                              void* d_out, int out_size, void* d_ws, size_t ws_size,
                              hipStream_t stream) {
  const float* hs   = (const float*)d_in[0];
  const float* wqkv = (const float*)d_in[1];
  const float* bqkv = (const float*)d_in[2];
  const float* wd   = (const float*)d_in[3];
  const float* bd   = (const float*)d_in[4];
  float* out = (float*)d_out;
  char* ws = (char*)d_ws;
  const size_t MB = 1u << 20;

  short* hs_bf  = (short*)(ws);            // 16 MB
  short* wqkv_t = (short*)(ws + 16 * MB);  //  6 MB
  short* wd_t   = (short*)(ws + 22 * MB);  //  2 MB
  short* qbuf   = (short*)(ws + 24 * MB);  // 16 MB: [64][2048][64]
  short* kbuf   = (short*)(ws + 40 * MB);  // 16 MB: [64][2048][64]
  short* vtbuf  = (short*)(ws + 56 * MB);  // 16 MB: [64][64][2048]
  short* ctx    = (short*)(ws + 72 * MB);  // 16 MB: [8192][1024]

  k_pre<<<12288, 256, 0, stream>>>(hs, hs_bf, wqkv, wqkv_t, wd, wd_t);
  k_gemm<0><<<dim3(24, 64), 256, 0, stream>>>(hs_bf, wqkv_t, bqkv,
                                              qbuf, kbuf, vtbuf, nullptr, 1024);
  k_attn<<<1024, 512, 0, stream>>>(qbuf, kbuf, vtbuf, ctx);
  k_gemm<1><<<dim3(8, 64), 256, 0, stream>>>(ctx, wd_t, bd,
                                             nullptr, nullptr, nullptr, out, 1024);
}